// Round 2
// baseline (180.399 us; speedup 1.0000x reference)
//
#include <hip/hip_runtime.h>
#include <hip/hip_bf16.h>
#include <stdint.h>

typedef __attribute__((ext_vector_type(8))) short short8;
typedef __attribute__((ext_vector_type(4))) float f32x4;

__device__ __forceinline__ short f2bf(float f) {
    unsigned u = __builtin_bit_cast(unsigned, f);
    return (short)((u + 0x8000u) >> 16);   // round-half-up to bf16
}
__device__ __forceinline__ float bf2f(short s) {
    unsigned u = ((unsigned)(unsigned short)s) << 16;
    return __builtin_bit_cast(float, u);
}

// ---------------------------------------------------------------------------
// Kernel 1: transpose + fp32->bf16 convert W -> BT (for contiguous-k B frags).
// W0: (8,128,64) f32 -> BT0: (512,128) bf16   BT0[h*64+dd][k] = W0[h][k][dd]
// W1: (8,512,64) f32 -> BT1: (512,512) bf16
// ---------------------------------------------------------------------------
__global__ void wtrans_kernel(const float* __restrict__ W0, const float* __restrict__ W1,
                              short* __restrict__ BT0, short* __restrict__ BT1) {
    int idx = blockIdx.x * 256 + threadIdx.x;
    if (idx < 8 * 128 * 64) {
        int h = idx >> 13;            // / (128*64)
        int k = (idx >> 6) & 127;
        int dd = idx & 63;
        BT0[(h * 64 + dd) * 128 + k] = f2bf(W0[idx]);
    } else {
        int j = idx - 8 * 128 * 64;   // W1 region
        int h = j >> 15;              // / (512*64)
        int k = (j >> 6) & 511;
        int dd = j & 63;
        BT1[(h * 64 + dd) * 512 + k] = f2bf(W1[j]);
    }
}

// ---------------------------------------------------------------------------
// Kernel 2: GEMM  C(16384 x 512) = A(16384 x K) @ B(K x 512), B given as BT(512 x K) bf16.
// A is fp32 (stack 0, converted during staging) or bf16 (stack 1).
// Output written TRANSPOSED per head: fts[(h*32+b)*64 + dd][n]  (bf16)
// 128x128 tile, 4 waves of 64x64, 16x16x32 bf16 MFMA, BK=32.
// ---------------------------------------------------------------------------
template <typename AT>
__global__ __launch_bounds__(256, 2)
void gemm_kernel(const AT* __restrict__ A, const short* __restrict__ BT,
                 short* __restrict__ fts, int K) {
    __shared__ __align__(16) short As[128 * 40];  // +8 pad -> benign 2-way bank alias on b128
    __shared__ __align__(16) short Bs[128 * 40];

    const int tid  = threadIdx.x;
    const int lane = tid & 63;
    const int w    = tid >> 6;
    const int wr   = w >> 1, wc = w & 1;
    const int quad = lane >> 4, l15 = lane & 15;
    const int m0   = blockIdx.y * 128;
    const int n0   = blockIdx.x * 128;

    f32x4 acc[4][4];
    for (int i = 0; i < 4; ++i)
        for (int j = 0; j < 4; ++j) { f32x4 z = {0.f, 0.f, 0.f, 0.f}; acc[i][j] = z; }

    const int nkb = K >> 5;
    for (int kb = 0; kb < nkb; ++kb) {
        __syncthreads();
        if constexpr (sizeof(AT) == 4) {
            // fp32 A: 1024 float4 chunks (4 floats each), convert to bf16
            for (int i = 0; i < 4; ++i) {
                int id  = tid + i * 256;
                int row = id >> 3, kc = id & 7;
                float4 v = *(const float4*)((const float*)A + (size_t)(m0 + row) * K + kb * 32 + kc * 4);
                ushort4 p;
                p.x = (unsigned short)f2bf(v.x);
                p.y = (unsigned short)f2bf(v.y);
                p.z = (unsigned short)f2bf(v.z);
                p.w = (unsigned short)f2bf(v.w);
                *(ushort4*)(As + row * 40 + kc * 4) = p;
            }
        } else {
            // bf16 A: 512 16B chunks
            for (int i = 0; i < 2; ++i) {
                int id  = tid + i * 256;
                int row = id >> 2, kc = id & 3;
                uint4 va = *(const uint4*)((const short*)A + (size_t)(m0 + row) * K + kb * 32 + kc * 8);
                *(uint4*)(As + row * 40 + kc * 8) = va;
            }
        }
        for (int i = 0; i < 2; ++i) {          // 512 16B chunks for B
            int id  = tid + i * 256;
            int row = id >> 2, kc = id & 3;
            uint4 vb = *(const uint4*)(BT + (size_t)(n0 + row) * K + kb * 32 + kc * 8);
            *(uint4*)(Bs + row * 40 + kc * 8) = vb;
        }
        __syncthreads();
        short8 af[4], bf[4];
        for (int mf = 0; mf < 4; ++mf)
            af[mf] = *(const short8*)(As + (wr * 64 + mf * 16 + l15) * 40 + quad * 8);
        for (int nf = 0; nf < 4; ++nf)
            bf[nf] = *(const short8*)(Bs + (wc * 64 + nf * 16 + l15) * 40 + quad * 8);
        for (int mf = 0; mf < 4; ++mf)
            for (int nf = 0; nf < 4; ++nf)
                acc[mf][nf] = __builtin_amdgcn_mfma_f32_16x16x32_bf16(af[mf], bf[nf], acc[mf][nf], 0, 0, 0);
    }

    // epilogue: transposed store  fts[((h*32+b)*64+dd)*512 + n], 4 consecutive n -> 8B
    for (int nf = 0; nf < 4; ++nf) {
        int col = n0 + wc * 64 + nf * 16 + l15;   // global column in [0,512) = h*64+dd
        int h = col >> 6, dd = col & 63;
        for (int mf = 0; mf < 4; ++mf) {
            int m = m0 + wr * 64 + mf * 16 + quad * 4;   // rows quad*4 + r
            int b = m >> 9, n = m & 511;
            ushort4 pk;
            pk.x = (unsigned short)f2bf(acc[mf][nf][0]);
            pk.y = (unsigned short)f2bf(acc[mf][nf][1]);
            pk.z = (unsigned short)f2bf(acc[mf][nf][2]);
            pk.w = (unsigned short)f2bf(acc[mf][nf][3]);
            *(ushort4*)(fts + (size_t)((h * 32 + b) * 64 + dd) * 512 + n) = pk;
        }
    }
}

// ---------------------------------------------------------------------------
// Kernel 3: fused GAT attention for one (h, b, row-half).
//   scores s(i,j) = leaky_relu(f1[i] + f2[j]);  e = exp(s)  (no max needed: |s| < ~5)
//   O[i,:] = sum_j e * fts[j,:];  L[i] = sum_j e;  out = elu(O/L + fts[i,:])
// fts is bf16 transposed (h,b,dd,n). Staged in two 256-j chunks, 16B-chunk XOR swizzle.
// a-vectors are fp32. OutT = short (bf16 intermediate) or float (final output).
// ---------------------------------------------------------------------------
template <typename OutT>
__global__ __launch_bounds__(256, 2)
void attn_kernel(const short* __restrict__ fts,
                 const float* __restrict__ a1w, const float* __restrict__ a1b,
                 const float* __restrict__ a2w, const float* __restrict__ a2b,
                 OutT* __restrict__ out) {
    __shared__ __align__(16) short fts_s[64 * 256];  // 32KB: 64 dd-rows x 256 j, swizzled
    __shared__ float f1_s[256];
    __shared__ __align__(16) float f2_s[512];

    const int tid  = threadIdx.x;
    const int lane = tid & 63, w = tid >> 6;
    const int quad = lane >> 4, l15 = lane & 15;
    const int bx   = blockIdx.x;
    const int h    = bx >> 6;
    const int b    = (bx >> 1) & 31;
    const int half = bx & 1;
    const size_t fbase = (size_t)((h * 32 + b) * 64) * 512;

    f32x4 acc[4][4];
    for (int i = 0; i < 4; ++i)
        for (int j = 0; j < 4; ++j) { f32x4 z = {0.f, 0.f, 0.f, 0.f}; acc[i][j] = z; }
    float Lp[4] = {0.f, 0.f, 0.f, 0.f};

    const float a1bf = a1b[h], a2bf = a2b[h];

    // ---- stage chunk c + compute f1/f2 from it
    for (int c = 0; c < 2; ++c) {
        __syncthreads();
        for (int i = 0; i < 8; ++i) {
            int id = tid + i * 256;
            int dd = id >> 5, nc = id & 31;
            uint4 v = *(const uint4*)(fts + fbase + dd * 512 + c * 256 + nc * 8);
            *(uint4*)(fts_s + dd * 256 + ((nc ^ (dd & 7)) << 3)) = v;
        }
        __syncthreads();
        {   // one j-row per thread
            int j = tid;
            float s1 = 0.f, s2 = 0.f;
            for (int dd = 0; dd < 64; ++dd) {
                float v = bf2f(fts_s[dd * 256 + (((j >> 3) ^ (dd & 7)) << 3) + (j & 7)]);
                s1 += v * a1w[h * 64 + dd];
                s2 += v * a2w[h * 64 + dd];
            }
            f2_s[c * 256 + j] = s2 + a2bf;
            if (c == half) f1_s[j] = s1 + a1bf;   // f1 only for this block's own rows
        }
    }
    __syncthreads();

    float f1v[4];
    for (int rt = 0; rt < 4; ++rt) f1v[rt] = f1_s[w * 64 + rt * 16 + l15];

    // ---- main loop: chunk 1 (currently resident), then restage chunk 0
    for (int ci = 0; ci < 2; ++ci) {
        const int c = 1 - ci;
        if (ci == 1) {
            __syncthreads();
            for (int i = 0; i < 8; ++i) {
                int id = tid + i * 256;
                int dd = id >> 5, nc = id & 31;
                uint4 v = *(const uint4*)(fts + fbase + dd * 512 + nc * 8);  // chunk 0
                *(uint4*)(fts_s + dd * 256 + ((nc ^ (dd & 7)) << 3)) = v;
            }
            __syncthreads();
        }
        for (int jb = 0; jb < 8; ++jb) {        // 32 j per step
            short8 bfr[4];
            for (int nf = 0; nf < 4; ++nf) {    // B-frag: fts[j..j+8)[dd=col], contiguous j
                int col = nf * 16 + l15;
                bfr[nf] = *(const short8*)(fts_s + col * 256 + (((jb * 4 + quad) ^ (col & 7)) << 3));
            }
            const float* fp = &f2_s[c * 256 + jb * 32 + quad * 8];
            f32x4 fa = *(const f32x4*)fp;
            f32x4 fb = *(const f32x4*)(fp + 4);
            float f2v[8] = {fa[0], fa[1], fa[2], fa[3], fb[0], fb[1], fb[2], fb[3]};

            for (int rt = 0; rt < 4; ++rt) {    // E-frag in A-layout: m=l15, k=quad*8+t
                short8 ef;
                float f1r = f1v[rt];
                float lsum = 0.f;
                for (int t = 0; t < 8; ++t) {
                    float s = f1r + f2v[t];
                    s = fmaxf(s, 0.01f * s);                       // leaky_relu
                    float ev = __builtin_amdgcn_exp2f(s * 1.44269504f);
                    lsum += ev;
                    ef[t] = f2bf(ev);
                }
                Lp[rt] += lsum;
                for (int nf = 0; nf < 4; ++nf)
                    acc[rt][nf] = __builtin_amdgcn_mfma_f32_16x16x32_bf16(ef, bfr[nf], acc[rt][nf], 0, 0, 0);
            }
        }
    }

    // ---- epilogue: L reduce, normalize, residual, ELU, store
    const int r0 = half * 256;
    for (int rt = 0; rt < 4; ++rt) {
        float Lf = Lp[rt];
        Lf += __shfl_xor(Lf, 16, 64);
        Lf += __shfl_xor(Lf, 32, 64);           // full L for row l15
        float rinv[4];
        for (int r = 0; r < 4; ++r) {
            float Lr = __shfl(Lf, quad * 4 + r, 64);
            rinv[r] = __builtin_amdgcn_rcpf(Lr);
        }
        int i0 = r0 + w * 64 + rt * 16 + quad * 4;
        for (int nf = 0; nf < 4; ++nf) {
            int col = nf * 16 + l15;            // dd
            ushort4 res = *(const ushort4*)(fts + fbase + col * 512 + i0);
            unsigned short rr[4] = {res.x, res.y, res.z, res.w};
            for (int r = 0; r < 4; ++r) {
                float val = acc[rt][nf][r] * rinv[r] + bf2f((short)rr[r]);
                if (val < 0.f) val = __builtin_amdgcn_exp2f(val * 1.44269504f) - 1.f;  // elu
                size_t oidx = (size_t)(b * 512 + i0 + r) * 512 + h * 64 + col;
                if constexpr (sizeof(OutT) == 4) out[oidx] = val;
                else                             out[oidx] = f2bf(val);
            }
        }
    }
}

// ---------------------------------------------------------------------------
extern "C" void kernel_launch(void* const* d_in, const int* in_sizes, int n_in,
                              void* d_out, int out_size, void* d_ws, size_t ws_size,
                              hipStream_t stream) {
    const float* x   = (const float*)d_in[0];   // (32,512,128) f32
    const float* W0  = (const float*)d_in[1];   // (8,128,64)
    const float* W1  = (const float*)d_in[2];   // (8,512,64)
    const float* a1w = (const float*)d_in[3];   // (2,8,64)
    const float* a1b = (const float*)d_in[4];   // (2,8)
    const float* a2w = (const float*)d_in[5];   // (2,8,64)
    const float* a2b = (const float*)d_in[6];   // (2,8)
    float* out = (float*)d_out;                 // (32,512,512) f32

    char* ws = (char*)d_ws;
    short* BT0 = (short*)(ws);                  // 512x128 bf16 (131072 B)
    short* BT1 = (short*)(ws + 131072);         // 512x512 bf16 (524288 B)
    short* fts = (short*)(ws + 655360);         // (8,32,64,512) bf16 (16.78 MB)
    // bf16 hidden activations live in d_out's first 16MB: read only by gemm1,
    // then fully overwritten (fp32) by the final attn kernel. Stream-serialized.
    short* hbuf = (short*)d_out;

    wtrans_kernel<<<1280, 256, 0, stream>>>(W0, W1, BT0, BT1);

    // stack 0
    gemm_kernel<float><<<dim3(4, 128), 256, 0, stream>>>(x, BT0, fts, 128);
    attn_kernel<short><<<512, 256, 0, stream>>>(fts, a1w, a1b, a2w, a2b, hbuf);

    // stack 1
    gemm_kernel<short><<<dim3(4, 128), 256, 0, stream>>>(hbuf, BT1, fts, 512);
    attn_kernel<float><<<512, 256, 0, stream>>>(fts, a1w + 512, a1b + 8, a2w + 512, a2b + 8, out);
}

// Round 3
// 176.865 us; speedup vs baseline: 1.0200x; 1.0200x over previous
//
#include <hip/hip_runtime.h>
#include <hip/hip_bf16.h>
#include <stdint.h>

typedef __attribute__((ext_vector_type(8))) short short8;
typedef __attribute__((ext_vector_type(4))) float f32x4;

#define L2E 1.44269504f

__device__ __forceinline__ short f2bf(float f) {
    unsigned u = __builtin_bit_cast(unsigned, f);
    return (short)((u + 0x8000u) >> 16);   // round-half-up to bf16
}
__device__ __forceinline__ float bf2f(short s) {
    unsigned u = ((unsigned)(unsigned short)s) << 16;
    return __builtin_bit_cast(float, u);
}

// ---------------------------------------------------------------------------
// Kernel 1: transpose + fp32->bf16 convert W -> BT (for contiguous-k B frags).
// W0: (8,128,64) f32 -> BT0: (512,128) bf16   BT0[h*64+dd][k] = W0[h][k][dd]
// W1: (8,512,64) f32 -> BT1: (512,512) bf16
// ---------------------------------------------------------------------------
__global__ void wtrans_kernel(const float* __restrict__ W0, const float* __restrict__ W1,
                              short* __restrict__ BT0, short* __restrict__ BT1) {
    int idx = blockIdx.x * 256 + threadIdx.x;
    if (idx < 8 * 128 * 64) {
        int h = idx >> 13;            // / (128*64)
        int k = (idx >> 6) & 127;
        int dd = idx & 63;
        BT0[(h * 64 + dd) * 128 + k] = f2bf(W0[idx]);
    } else {
        int j = idx - 8 * 128 * 64;   // W1 region
        int h = j >> 15;              // / (512*64)
        int k = (j >> 6) & 511;
        int dd = j & 63;
        BT1[(h * 64 + dd) * 512 + k] = f2bf(W1[j]);
    }
}

// ---------------------------------------------------------------------------
// Kernel 2: GEMM  C(16384 x 512) = A(16384 x K) @ B(K x 512), B given as BT(512 x K) bf16.
// A is fp32 (stack 0, converted during staging) or bf16 (stack 1).
// Output written TRANSPOSED per head: fts[(h*32+b)*64 + dd][n]  (bf16)
// 128x128 tile, 4 waves of 64x64, 16x16x32 bf16 MFMA, BK=32.
// ---------------------------------------------------------------------------
template <typename AT>
__global__ __launch_bounds__(256, 2)
void gemm_kernel(const AT* __restrict__ A, const short* __restrict__ BT,
                 short* __restrict__ fts, int K) {
    __shared__ __align__(16) short As[128 * 40];  // +8 pad -> benign 2-way bank alias on b128
    __shared__ __align__(16) short Bs[128 * 40];

    const int tid  = threadIdx.x;
    const int lane = tid & 63;
    const int w    = tid >> 6;
    const int wr   = w >> 1, wc = w & 1;
    const int quad = lane >> 4, l15 = lane & 15;
    const int m0   = blockIdx.y * 128;
    const int n0   = blockIdx.x * 128;

    f32x4 acc[4][4];
    for (int i = 0; i < 4; ++i)
        for (int j = 0; j < 4; ++j) { f32x4 z = {0.f, 0.f, 0.f, 0.f}; acc[i][j] = z; }

    const int nkb = K >> 5;
    for (int kb = 0; kb < nkb; ++kb) {
        __syncthreads();
        if constexpr (sizeof(AT) == 4) {
            // fp32 A: 1024 float4 chunks (4 floats each), convert to bf16
            for (int i = 0; i < 4; ++i) {
                int id  = tid + i * 256;
                int row = id >> 3, kc = id & 7;
                float4 v = *(const float4*)((const float*)A + (size_t)(m0 + row) * K + kb * 32 + kc * 4);
                ushort4 p;
                p.x = (unsigned short)f2bf(v.x);
                p.y = (unsigned short)f2bf(v.y);
                p.z = (unsigned short)f2bf(v.z);
                p.w = (unsigned short)f2bf(v.w);
                *(ushort4*)(As + row * 40 + kc * 4) = p;
            }
        } else {
            // bf16 A: 512 16B chunks
            for (int i = 0; i < 2; ++i) {
                int id  = tid + i * 256;
                int row = id >> 2, kc = id & 3;
                uint4 va = *(const uint4*)((const short*)A + (size_t)(m0 + row) * K + kb * 32 + kc * 8);
                *(uint4*)(As + row * 40 + kc * 8) = va;
            }
        }
        for (int i = 0; i < 2; ++i) {          // 512 16B chunks for B
            int id  = tid + i * 256;
            int row = id >> 2, kc = id & 3;
            uint4 vb = *(const uint4*)(BT + (size_t)(n0 + row) * K + kb * 32 + kc * 8);
            *(uint4*)(Bs + row * 40 + kc * 8) = vb;
        }
        __syncthreads();
        short8 af[4], bf[4];
        for (int mf = 0; mf < 4; ++mf)
            af[mf] = *(const short8*)(As + (wr * 64 + mf * 16 + l15) * 40 + quad * 8);
        for (int nf = 0; nf < 4; ++nf)
            bf[nf] = *(const short8*)(Bs + (wc * 64 + nf * 16 + l15) * 40 + quad * 8);
        for (int mf = 0; mf < 4; ++mf)
            for (int nf = 0; nf < 4; ++nf)
                acc[mf][nf] = __builtin_amdgcn_mfma_f32_16x16x32_bf16(af[mf], bf[nf], acc[mf][nf], 0, 0, 0);
    }

    // epilogue: transposed store  fts[((h*32+b)*64+dd)*512 + n], 4 consecutive n -> 8B
    for (int nf = 0; nf < 4; ++nf) {
        int col = n0 + wc * 64 + nf * 16 + l15;   // global column in [0,512) = h*64+dd
        int h = col >> 6, dd = col & 63;
        for (int mf = 0; mf < 4; ++mf) {
            int m = m0 + wr * 64 + mf * 16 + quad * 4;   // rows quad*4 + r
            int b = m >> 9, n = m & 511;
            ushort4 pk;
            pk.x = (unsigned short)f2bf(acc[mf][nf][0]);
            pk.y = (unsigned short)f2bf(acc[mf][nf][1]);
            pk.z = (unsigned short)f2bf(acc[mf][nf][2]);
            pk.w = (unsigned short)f2bf(acc[mf][nf][3]);
            *(ushort4*)(fts + (size_t)((h * 32 + b) * 64 + dd) * 512 + n) = pk;
        }
    }
}

// ---------------------------------------------------------------------------
// Kernel 3: fused GAT attention. One block = (h, b, 128-row quarter).
//   e(i,j) = exp(leaky_relu(f1_i + f2_j))
//          = (f1+f2 >= 0) ? e^f1 * e^f2 : e^{.01 f1} * e^{.01 f2}   (factorized!)
//   O[i,:] = sum_j e * fts[j,:];  L[i] = sum_j e;  out = elu(O/L + fts[i,:])
// fts is bf16 transposed (h,b,dd,n). j staged in two 256-chunks (own-row chunk
// first so f1 is available; no restage). 16B-chunk XOR swizzle kills conflicts.
// ---------------------------------------------------------------------------
template <typename OutT>
__global__ __launch_bounds__(256, 4)
void attn_kernel(const short* __restrict__ fts,
                 const float* __restrict__ a1w, const float* __restrict__ a1b,
                 const float* __restrict__ a2w, const float* __restrict__ a2b,
                 OutT* __restrict__ out) {
    __shared__ __align__(16) short fts_s[64 * 256];  // 32KB: 64 dd-rows x 256 j, swizzled
    __shared__ float f1_s[128];
    __shared__ __align__(16) float f2_s[256];
    __shared__ __align__(16) float p2_s[256];
    __shared__ __align__(16) float q2_s[256];

    const int tid  = threadIdx.x;
    const int lane = tid & 63, w = tid >> 6;
    const int quad = lane >> 4, l15 = lane & 15;
    const int bx   = blockIdx.x;
    const int h    = bx >> 7;
    const int b    = (bx >> 2) & 31;
    const int quarter = bx & 3;
    const int r0   = quarter * 128;      // this block's row base
    const int c0   = quarter >> 1;       // chunk containing own rows
    const size_t fbase = (size_t)((h * 32 + b) * 64) * 512;

    f32x4 acc[2][4];
    for (int i = 0; i < 2; ++i)
        for (int j = 0; j < 4; ++j) { f32x4 z = {0.f, 0.f, 0.f, 0.f}; acc[i][j] = z; }
    float Lp[2] = {0.f, 0.f};
    float f1r[2], P1r[2], Q1r[2];

    const float a1bf = a1b[h], a2bf = a2b[h];

    for (int ci = 0; ci < 2; ++ci) {
        const int c = (ci == 0) ? c0 : 1 - c0;   // own-row chunk first
        __syncthreads();
        // ---- stage 256-j chunk (swizzled)
        for (int i = 0; i < 8; ++i) {
            int id = tid + i * 256;
            int dd = id >> 5, nc = id & 31;
            uint4 v = *(const uint4*)(fts + fbase + dd * 512 + c * 256 + nc * 8);
            *(uint4*)(fts_s + dd * 256 + ((nc ^ (dd & 7)) << 3)) = v;
        }
        __syncthreads();
        // ---- f-phase: one column per thread -> f2/P2/Q2 (and f1 for own rows)
        {
            int j = tid;
            float s1 = 0.f, s2 = 0.f;
            for (int dd = 0; dd < 64; ++dd) {
                float v = bf2f(fts_s[dd * 256 + (((j >> 3) ^ (dd & 7)) << 3) + (j & 7)]);
                s1 += v * a1w[h * 64 + dd];
                s2 += v * a2w[h * 64 + dd];
            }
            float f2 = s2 + a2bf;
            f2_s[j] = f2;
            p2_s[j] = __builtin_amdgcn_exp2f(f2 * L2E);
            q2_s[j] = __builtin_amdgcn_exp2f(f2 * (0.01f * L2E));
            if (ci == 0) {
                int lo = r0 & 255;               // own rows inside this chunk
                if (((unsigned)(j - lo)) < 128u) f1_s[j - lo] = s1 + a1bf;
            }
        }
        __syncthreads();
        if (ci == 0) {
            for (int rt = 0; rt < 2; ++rt) {
                float f1 = f1_s[w * 32 + rt * 16 + l15];
                f1r[rt] = f1;
                P1r[rt] = __builtin_amdgcn_exp2f(f1 * L2E);
                Q1r[rt] = __builtin_amdgcn_exp2f(f1 * (0.01f * L2E));
            }
        }
        // ---- main loop: 32 j per step
        for (int jb = 0; jb < 8; ++jb) {
            short8 bfr[4];
            for (int nf = 0; nf < 4; ++nf) {    // B-frag: fts[j..j+8)[dd=col], contiguous j
                int col = nf * 16 + l15;
                bfr[nf] = *(const short8*)(fts_s + col * 256 + (((jb * 4 + quad) ^ (col & 7)) << 3));
            }
            int o = jb * 32 + quad * 8;
            f32x4 fa = *(const f32x4*)(f2_s + o), fb = *(const f32x4*)(f2_s + o + 4);
            f32x4 pa = *(const f32x4*)(p2_s + o), pb = *(const f32x4*)(p2_s + o + 4);
            f32x4 qa = *(const f32x4*)(q2_s + o), qb = *(const f32x4*)(q2_s + o + 4);
            float f2v[8] = {fa[0], fa[1], fa[2], fa[3], fb[0], fb[1], fb[2], fb[3]};
            float p2v[8] = {pa[0], pa[1], pa[2], pa[3], pb[0], pb[1], pb[2], pb[3]};
            float q2v[8] = {qa[0], qa[1], qa[2], qa[3], qb[0], qb[1], qb[2], qb[3]};

            for (int rt = 0; rt < 2; ++rt) {    // E-frag in A-layout: m=l15, k=quad*8+t
                short8 ef;
                float lsum = 0.f;
                for (int t = 0; t < 8; ++t) {
                    float s = f1r[rt] + f2v[t];
                    float e = (s < 0.f) ? (Q1r[rt] * q2v[t]) : (P1r[rt] * p2v[t]);
                    lsum += e;
                    ef[t] = f2bf(e);
                }
                Lp[rt] += lsum;
                for (int nf = 0; nf < 4; ++nf)
                    acc[rt][nf] = __builtin_amdgcn_mfma_f32_16x16x32_bf16(ef, bfr[nf], acc[rt][nf], 0, 0, 0);
            }
        }
    }

    // ---- epilogue: L reduce, normalize, residual, ELU, store
    for (int rt = 0; rt < 2; ++rt) {
        float Lf = Lp[rt];
        Lf += __shfl_xor(Lf, 16, 64);
        Lf += __shfl_xor(Lf, 32, 64);           // full L for row l15
        float rinv[4];
        for (int r = 0; r < 4; ++r) {
            float Lr = __shfl(Lf, quad * 4 + r, 64);
            rinv[r] = __builtin_amdgcn_rcpf(Lr);
        }
        int i0 = r0 + w * 32 + rt * 16 + quad * 4;
        for (int nf = 0; nf < 4; ++nf) {
            int col = nf * 16 + l15;            // dd
            ushort4 res = *(const ushort4*)(fts + fbase + col * 512 + i0);
            unsigned short rr[4] = {res.x, res.y, res.z, res.w};
            for (int r = 0; r < 4; ++r) {
                float val = acc[rt][nf][r] * rinv[r] + bf2f((short)rr[r]);
                if (val < 0.f) val = __builtin_amdgcn_exp2f(val * L2E) - 1.f;  // elu
                size_t oidx = (size_t)(b * 512 + i0 + r) * 512 + h * 64 + col;
                if constexpr (sizeof(OutT) == 4) out[oidx] = val;
                else                             out[oidx] = f2bf(val);
            }
        }
    }
}

// ---------------------------------------------------------------------------
extern "C" void kernel_launch(void* const* d_in, const int* in_sizes, int n_in,
                              void* d_out, int out_size, void* d_ws, size_t ws_size,
                              hipStream_t stream) {
    const float* x   = (const float*)d_in[0];   // (32,512,128) f32
    const float* W0  = (const float*)d_in[1];   // (8,128,64)
    const float* W1  = (const float*)d_in[2];   // (8,512,64)
    const float* a1w = (const float*)d_in[3];   // (2,8,64)
    const float* a1b = (const float*)d_in[4];   // (2,8)
    const float* a2w = (const float*)d_in[5];   // (2,8,64)
    const float* a2b = (const float*)d_in[6];   // (2,8)
    float* out = (float*)d_out;                 // (32,512,512) f32

    char* ws = (char*)d_ws;
    short* BT0 = (short*)(ws);                  // 512x128 bf16 (131072 B)
    short* BT1 = (short*)(ws + 131072);         // 512x512 bf16 (524288 B)
    short* fts = (short*)(ws + 655360);         // (8,32,64,512) bf16 (16.78 MB)
    // bf16 hidden activations live in d_out's first 16MB: read only by gemm1,
    // then fully overwritten (fp32) by the final attn kernel. Stream-serialized.
    short* hbuf = (short*)d_out;

    wtrans_kernel<<<1280, 256, 0, stream>>>(W0, W1, BT0, BT1);

    // stack 0
    gemm_kernel<float><<<dim3(4, 128), 256, 0, stream>>>(x, BT0, fts, 128);
    attn_kernel<short><<<1024, 256, 0, stream>>>(fts, a1w, a1b, a2w, a2b, hbuf);

    // stack 1
    gemm_kernel<short><<<dim3(4, 128), 256, 0, stream>>>(hbuf, BT1, fts, 512);
    attn_kernel<float><<<1024, 256, 0, stream>>>(fts, a1w + 512, a1b + 8, a2w + 512, a2b + 8, out);
}

// Round 4
// 167.089 us; speedup vs baseline: 1.0797x; 1.0585x over previous
//
#include <hip/hip_runtime.h>
#include <hip/hip_bf16.h>
#include <stdint.h>

typedef __attribute__((ext_vector_type(8))) short short8;
typedef __attribute__((ext_vector_type(4))) float f32x4;

#define L2E 1.44269504f
#define FN  131072              // elements per f-array: H*B*N = 8*32*512

__device__ __forceinline__ short f2bf(float f) {
    unsigned u = __builtin_bit_cast(unsigned, f);
    return (short)((u + 0x8000u) >> 16);   // round-half-up to bf16
}
__device__ __forceinline__ float bf2f(short s) {
    unsigned u = ((unsigned)(unsigned short)s) << 16;
    return __builtin_bit_cast(float, u);
}

// async global->LDS, 16B per lane; LDS dest = wave-uniform base + lane*16
__device__ __forceinline__ void gld16(void* l, const void* g) {
    __builtin_amdgcn_global_load_lds(
        (const __attribute__((address_space(1))) unsigned*)g,
        (__attribute__((address_space(3))) unsigned*)l, 16, 0, 0);
}

// ---------------------------------------------------------------------------
// Kernel 1: transpose + fp32->bf16 convert W -> BT.
// W0: (8,128,64) f32 -> BT0: (512,128) bf16   BT0[h*64+dd][k] = W0[h][k][dd]
// W1: (8,512,64) f32 -> BT1: (512,512) bf16
// ---------------------------------------------------------------------------
__global__ void wtrans_kernel(const float* __restrict__ W0, const float* __restrict__ W1,
                              short* __restrict__ BT0, short* __restrict__ BT1) {
    int idx = blockIdx.x * 256 + threadIdx.x;
    if (idx < 8 * 128 * 64) {
        int h = idx >> 13;
        int k = (idx >> 6) & 127;
        int dd = idx & 63;
        BT0[(h * 64 + dd) * 128 + k] = f2bf(W0[idx]);
    } else {
        int j = idx - 8 * 128 * 64;
        int h = j >> 15;
        int k = (j >> 6) & 511;
        int dd = j & 63;
        BT1[(h * 64 + dd) * 512 + k] = f2bf(W1[j]);
    }
}

// ---------------------------------------------------------------------------
// Kernel 2: GEMM  C(16384 x 512) = A(16384 x K) @ BT(512 x K)^T, bf16 MFMA.
// A fp32 (stack0, converted during manual staging) or bf16 (stack1, async LDS).
// fts written transposed per head: fts[(h*32+b)*64+dd][n] bf16.
// Epilogue also computes f1/f2 = fts @ a-vec (+bias) from the fp32 acc and
// writes fp32 f1,P1=e^f1,Q1=e^.01f1,f2,P2,Q2 arrays (indexed (h*32+b)*512+i).
// LDS: unpadded 32-short rows, chunk swizzle kc ^ ((row>>1)&3) -> <=2-way banks.
// ---------------------------------------------------------------------------
template <typename AT>
__global__ __launch_bounds__(256, 2)
void gemm_kernel(const AT* __restrict__ A, const short* __restrict__ BT,
                 short* __restrict__ fts, int K,
                 const float* __restrict__ a1w, const float* __restrict__ a1b,
                 const float* __restrict__ a2w, const float* __restrict__ a2b,
                 float* __restrict__ fbuf) {
    __shared__ __align__(16) short As[128 * 32];
    __shared__ __align__(16) short Bs[128 * 32];

    const int tid  = threadIdx.x;
    const int lane = tid & 63;
    const int w    = tid >> 6;
    const int wr   = w >> 1, wc = w & 1;
    const int quad = lane >> 4, l15 = lane & 15;
    const int m0   = blockIdx.y * 128;
    const int n0   = blockIdx.x * 128;

    // async-staging lane mapping (bf16 paths): 16 rows x 4 chunks per instr
    const int rl   = lane >> 2;            // row_local 0..15
    const int cpos = lane & 3;             // LDS chunk position
    const int kcl  = cpos ^ ((rl >> 1) & 3); // global chunk to fetch

    f32x4 acc[4][4];
    for (int i = 0; i < 4; ++i)
        for (int j = 0; j < 4; ++j) { f32x4 z = {0.f, 0.f, 0.f, 0.f}; acc[i][j] = z; }

    const int nkb = K >> 5;
    for (int kb = 0; kb < nkb; ++kb) {
        __syncthreads();
        if constexpr (sizeof(AT) == 4) {
            // fp32 A: manual convert-staging into the swizzled layout
            for (int i = 0; i < 4; ++i) {
                int id  = tid + i * 256;
                int row = id >> 3, q = id & 7;       // q: 4-float subchunk
                int kc = q >> 1, half = q & 1;
                float4 v = *(const float4*)((const float*)A + (size_t)(m0 + row) * K + kb * 32 + q * 4);
                ushort4 p;
                p.x = (unsigned short)f2bf(v.x);
                p.y = (unsigned short)f2bf(v.y);
                p.z = (unsigned short)f2bf(v.z);
                p.w = (unsigned short)f2bf(v.w);
                int swz = kc ^ ((row >> 1) & 3);
                *(ushort4*)(As + row * 32 + swz * 8 + half * 4) = p;
            }
        } else {
            for (int i = 0; i < 2; ++i) {            // async: 16 rows per instr
                int row = w * 32 + i * 16 + rl;
                gld16(As + (w * 32 + i * 16) * 32,
                      (const short*)A + (size_t)(m0 + row) * K + kb * 32 + kcl * 8);
            }
        }
        for (int i = 0; i < 2; ++i) {                // B always bf16 async
            int row = w * 32 + i * 16 + rl;
            gld16(Bs + (w * 32 + i * 16) * 32,
                  BT + (size_t)(n0 + row) * K + kb * 32 + kcl * 8);
        }
        __syncthreads();
        short8 af[4], bf[4];
        for (int mf = 0; mf < 4; ++mf) {
            int row = wr * 64 + mf * 16 + l15;
            af[mf] = *(const short8*)(As + row * 32 + ((quad ^ ((row >> 1) & 3)) << 3));
        }
        for (int nf = 0; nf < 4; ++nf) {
            int row = wc * 64 + nf * 16 + l15;
            bf[nf] = *(const short8*)(Bs + row * 32 + ((quad ^ ((row >> 1) & 3)) << 3));
        }
        for (int mf = 0; mf < 4; ++mf)
            for (int nf = 0; nf < 4; ++nf)
                acc[mf][nf] = __builtin_amdgcn_mfma_f32_16x16x32_bf16(af[mf], bf[nf], acc[mf][nf], 0, 0, 0);
    }

    // ---- epilogue A: transposed fts store
    for (int nf = 0; nf < 4; ++nf) {
        int col = n0 + wc * 64 + nf * 16 + l15;
        int h = col >> 6, dd = col & 63;
        for (int mf = 0; mf < 4; ++mf) {
            int m = m0 + wr * 64 + mf * 16 + quad * 4;
            int b = m >> 9, n = m & 511;
            ushort4 pk;
            pk.x = (unsigned short)f2bf(acc[mf][nf][0]);
            pk.y = (unsigned short)f2bf(acc[mf][nf][1]);
            pk.z = (unsigned short)f2bf(acc[mf][nf][2]);
            pk.w = (unsigned short)f2bf(acc[mf][nf][3]);
            *(ushort4*)(fts + (size_t)((h * 32 + b) * 64 + dd) * 512 + n) = pk;
        }
    }

    // ---- epilogue B: f1/f2 (+P,Q) from fp32 acc. head = n0/64 + wc, dd = nf*16+l15.
    {
        const int head = (n0 >> 6) + wc;
        float w1[4], w2[4];
        for (int nf = 0; nf < 4; ++nf) {
            w1[nf] = a1w[head * 64 + nf * 16 + l15];
            w2[nf] = a2w[head * 64 + nf * 16 + l15];
        }
        const float b1 = a1b[head], b2 = a2b[head];
        const int rsel = l15 & 3;
        for (int mf = 0; mf < 4; ++mf) {
            float g1[4], g2[4];
            for (int r = 0; r < 4; ++r) {
                float s1 = 0.f, s2 = 0.f;
                for (int nf = 0; nf < 4; ++nf) {
                    s1 += acc[mf][nf][r] * w1[nf];
                    s2 += acc[mf][nf][r] * w2[nf];
                }
                for (int m = 1; m < 16; m <<= 1) {
                    s1 += __shfl_xor(s1, m, 64);
                    s2 += __shfl_xor(s2, m, 64);
                }
                g1[r] = s1; g2[r] = s2;
            }
            float v1 = rsel == 0 ? g1[0] : rsel == 1 ? g1[1] : rsel == 2 ? g1[2] : g1[3];
            float v2 = rsel == 0 ? g2[0] : rsel == 1 ? g2[1] : rsel == 2 ? g2[2] : g2[3];
            if (l15 < 4) {
                int m = m0 + wr * 64 + mf * 16 + quad * 4 + rsel;
                int b = m >> 9, i = m & 511;
                int fi = (head * 32 + b) * 512 + i;
                float f1 = v1 + b1, f2 = v2 + b2;
                fbuf[0 * FN + fi] = f1;
                fbuf[1 * FN + fi] = __builtin_amdgcn_exp2f(f1 * L2E);
                fbuf[2 * FN + fi] = __builtin_amdgcn_exp2f(f1 * (0.01f * L2E));
                fbuf[3 * FN + fi] = f2;
                fbuf[4 * FN + fi] = __builtin_amdgcn_exp2f(f2 * L2E);
                fbuf[5 * FN + fi] = __builtin_amdgcn_exp2f(f2 * (0.01f * L2E));
            }
        }
    }
}

// ---------------------------------------------------------------------------
// Kernel 3: fused GAT attention. One block = (h, b, 128-row quarter).
//   e(i,j) = (f1_i+f2_j >= 0) ? P1_i*P2_j : Q1_i*Q2_j    (factorized exp)
//   O[i,:] = sum_j e * fts[j,:];  L[i] = sum_j e;  out = elu(O/L + fts[i,:])
// f-vectors precomputed by gemm. fts staged via async global_load_lds with
// source-side XOR swizzle (chunk nc^(dd&7) -> linear slot nc).
// ---------------------------------------------------------------------------
template <typename OutT>
__global__ __launch_bounds__(256, 4)
void attn_kernel(const short* __restrict__ fts, const float* __restrict__ fbuf,
                 OutT* __restrict__ out) {
    __shared__ __align__(16) short fts_s[64 * 256];  // 32KB, swizzled
    __shared__ __align__(16) float f2_s[256];
    __shared__ __align__(16) float p2_s[256];
    __shared__ __align__(16) float q2_s[256];

    const int tid  = threadIdx.x;
    const int lane = tid & 63, w = tid >> 6;
    const int quad = lane >> 4, l15 = lane & 15;
    const int bx   = blockIdx.x;
    const int h    = bx >> 7;
    const int b    = (bx >> 2) & 31;
    const int quarter = bx & 3;
    const int r0   = quarter * 128;
    const size_t fbase = (size_t)((h * 32 + b) * 64) * 512;
    const int fidx = (h * 32 + b) * 512;

    f32x4 acc[2][4];
    for (int i = 0; i < 2; ++i)
        for (int j = 0; j < 4; ++j) { f32x4 z = {0.f, 0.f, 0.f, 0.f}; acc[i][j] = z; }
    float Lp[2] = {0.f, 0.f};

    float f1r[2], P1r[2], Q1r[2];
    for (int rt = 0; rt < 2; ++rt) {
        int i = fidx + r0 + w * 32 + rt * 16 + l15;
        f1r[rt] = fbuf[i];
        P1r[rt] = fbuf[1 * FN + i];
        Q1r[rt] = fbuf[2 * FN + i];
    }

    for (int c = 0; c < 2; ++c) {
        __syncthreads();
        // stage fts 256-j chunk (async, source-swizzled) + f2/P2/Q2 slice
        for (int i = 0; i < 8; ++i) {
            int id = tid + i * 256;
            int dd = id >> 5, nc = id & 31;
            gld16(fts_s + (i * 256 + w * 64) * 8,
                  fts + fbase + dd * 512 + c * 256 + ((nc ^ (dd & 7)) << 3));
        }
        {
            int j = fidx + c * 256 + tid;
            f2_s[tid] = fbuf[3 * FN + j];
            p2_s[tid] = fbuf[4 * FN + j];
            q2_s[tid] = fbuf[5 * FN + j];
        }
        __syncthreads();

        for (int jb = 0; jb < 8; ++jb) {        // 32 j per step
            short8 bfr[4];
            for (int nf = 0; nf < 4; ++nf) {    // B-frag: fts[j..j+8)[dd=col]
                int col = nf * 16 + l15;
                bfr[nf] = *(const short8*)(fts_s + col * 256 + (((jb * 4 + quad) ^ (col & 7)) << 3));
            }
            int o = jb * 32 + quad * 8;
            f32x4 fa = *(const f32x4*)(f2_s + o), fb = *(const f32x4*)(f2_s + o + 4);
            f32x4 pa = *(const f32x4*)(p2_s + o), pb = *(const f32x4*)(p2_s + o + 4);
            f32x4 qa = *(const f32x4*)(q2_s + o), qb = *(const f32x4*)(q2_s + o + 4);
            float f2v[8] = {fa[0], fa[1], fa[2], fa[3], fb[0], fb[1], fb[2], fb[3]};
            float p2v[8] = {pa[0], pa[1], pa[2], pa[3], pb[0], pb[1], pb[2], pb[3]};
            float q2v[8] = {qa[0], qa[1], qa[2], qa[3], qb[0], qb[1], qb[2], qb[3]};

            for (int rt = 0; rt < 2; ++rt) {    // E-frag in A-layout: m=l15, k=quad*8+t
                short8 ef;
                float lsum = 0.f;
                for (int t = 0; t < 8; ++t) {
                    float s = f1r[rt] + f2v[t];
                    float e = (s < 0.f) ? (Q1r[rt] * q2v[t]) : (P1r[rt] * p2v[t]);
                    lsum += e;
                    ef[t] = f2bf(e);
                }
                Lp[rt] += lsum;
                for (int nf = 0; nf < 4; ++nf)
                    acc[rt][nf] = __builtin_amdgcn_mfma_f32_16x16x32_bf16(ef, bfr[nf], acc[rt][nf], 0, 0, 0);
            }
        }
    }

    // ---- epilogue: L reduce, normalize, residual, ELU, store
    for (int rt = 0; rt < 2; ++rt) {
        float Lf = Lp[rt];
        Lf += __shfl_xor(Lf, 16, 64);
        Lf += __shfl_xor(Lf, 32, 64);
        float rinv[4];
        for (int r = 0; r < 4; ++r) {
            float Lr = __shfl(Lf, quad * 4 + r, 64);
            rinv[r] = __builtin_amdgcn_rcpf(Lr);
        }
        int i0 = r0 + w * 32 + rt * 16 + quad * 4;
        for (int nf = 0; nf < 4; ++nf) {
            int col = nf * 16 + l15;
            ushort4 res = *(const ushort4*)(fts + fbase + col * 512 + i0);
            unsigned short rr[4] = {res.x, res.y, res.z, res.w};
            for (int r = 0; r < 4; ++r) {
                float val = acc[rt][nf][r] * rinv[r] + bf2f((short)rr[r]);
                if (val < 0.f) val = __builtin_amdgcn_exp2f(val * L2E) - 1.f;  // elu
                size_t oidx = (size_t)(b * 512 + i0 + r) * 512 + h * 64 + col;
                if constexpr (sizeof(OutT) == 4) out[oidx] = val;
                else                             out[oidx] = f2bf(val);
            }
        }
    }
}

// ---------------------------------------------------------------------------
extern "C" void kernel_launch(void* const* d_in, const int* in_sizes, int n_in,
                              void* d_out, int out_size, void* d_ws, size_t ws_size,
                              hipStream_t stream) {
    const float* x   = (const float*)d_in[0];   // (32,512,128) f32
    const float* W0  = (const float*)d_in[1];   // (8,128,64)
    const float* W1  = (const float*)d_in[2];   // (8,512,64)
    const float* a1w = (const float*)d_in[3];   // (2,8,64)
    const float* a1b = (const float*)d_in[4];   // (2,8)
    const float* a2w = (const float*)d_in[5];   // (2,8,64)
    const float* a2b = (const float*)d_in[6];   // (2,8)
    float* out = (float*)d_out;                 // (32,512,512) f32

    char* ws = (char*)d_ws;
    short* BT0  = (short*)(ws);                 // 512x128 bf16   (131072 B)
    short* BT1  = (short*)(ws + 131072);        // 512x512 bf16   (524288 B)
    float* fbuf = (float*)(ws + 655360);        // 6 x 131072 f32 (3145728 B)
    short* fts  = (short*)(ws + 3801088);       // (8,32,64,512) bf16 (16.78 MB)
    short* hbuf = (short*)d_out;                // bf16 hidden in d_out (overwritten later)

    wtrans_kernel<<<1280, 256, 0, stream>>>(W0, W1, BT0, BT1);

    // stack 0
    gemm_kernel<float><<<dim3(4, 128), 256, 0, stream>>>(x, BT0, fts, 128,
                                                         a1w, a1b, a2w, a2b, fbuf);
    attn_kernel<short><<<1024, 256, 0, stream>>>(fts, fbuf, hbuf);

    // stack 1
    gemm_kernel<short><<<dim3(4, 128), 256, 0, stream>>>(hbuf, BT1, fts, 512,
                                                         a1w + 512, a1b + 8, a2w + 512, a2b + 8, fbuf);
    attn_kernel<float><<<1024, 256, 0, stream>>>(fts, fbuf, out);
}

// Round 5
// 162.147 us; speedup vs baseline: 1.1126x; 1.0305x over previous
//
#include <hip/hip_runtime.h>
#include <hip/hip_bf16.h>
#include <stdint.h>

typedef __attribute__((ext_vector_type(8))) short short8;
typedef __attribute__((ext_vector_type(4))) float f32x4;

#define L2E 1.44269504f
#define FN  131072              // elements per f-array: H*B*N = 8*32*512

__device__ __forceinline__ short f2bf(float f) {
    unsigned u = __builtin_bit_cast(unsigned, f);
    return (short)((u + 0x8000u) >> 16);   // round-half-up to bf16
}
__device__ __forceinline__ float bf2f(short s) {
    unsigned u = ((unsigned)(unsigned short)s) << 16;
    return __builtin_bit_cast(float, u);
}

// async global->LDS, 16B per lane; LDS dest = wave-uniform base + lane*16
__device__ __forceinline__ void gld16(void* l, const void* g) {
    __builtin_amdgcn_global_load_lds(
        (const __attribute__((address_space(1))) unsigned*)g,
        (__attribute__((address_space(3))) unsigned*)l, 16, 0, 0);
}

// ---------------------------------------------------------------------------
// Kernel 1: transpose + fp32->bf16 convert W -> BT.
// ---------------------------------------------------------------------------
__global__ void wtrans_kernel(const float* __restrict__ W0, const float* __restrict__ W1,
                              short* __restrict__ BT0, short* __restrict__ BT1) {
    int idx = blockIdx.x * 256 + threadIdx.x;
    if (idx < 8 * 128 * 64) {
        int h = idx >> 13;
        int k = (idx >> 6) & 127;
        int dd = idx & 63;
        BT0[(h * 64 + dd) * 128 + k] = f2bf(W0[idx]);
    } else {
        int j = idx - 8 * 128 * 64;
        int h = j >> 15;
        int k = (j >> 6) & 511;
        int dd = j & 63;
        BT1[(h * 64 + dd) * 512 + k] = f2bf(W1[j]);
    }
}

// ---------------------------------------------------------------------------
// Kernel 2: GEMM  C(16384 x 512) = A(16384 x K) @ BT(512 x K)^T, bf16 MFMA.
// fts written transposed per head: fts[(h*32+b)*64+dd][n] bf16.
// Epilogue computes f1/f2 = fts @ a-vec (+bias) from fp32 acc and stores
// P1=e^f1, Q1=e^{.01 f1}, P2=e^f2, Q2=e^{.01 f2}  (fbuf[0..3], idx (h*32+b)*512+i).
// LDS: unpadded 32-short rows, chunk swizzle kc ^ ((row>>1)&3) -> <=2-way banks.
// ---------------------------------------------------------------------------
template <typename AT>
__global__ __launch_bounds__(256, 2)
void gemm_kernel(const AT* __restrict__ A, const short* __restrict__ BT,
                 short* __restrict__ fts, int K,
                 const float* __restrict__ a1w, const float* __restrict__ a1b,
                 const float* __restrict__ a2w, const float* __restrict__ a2b,
                 float* __restrict__ fbuf) {
    __shared__ __align__(16) short As[128 * 32];
    __shared__ __align__(16) short Bs[128 * 32];

    const int tid  = threadIdx.x;
    const int lane = tid & 63;
    const int w    = tid >> 6;
    const int wr   = w >> 1, wc = w & 1;
    const int quad = lane >> 4, l15 = lane & 15;
    const int m0   = blockIdx.y * 128;
    const int n0   = blockIdx.x * 128;

    const int rl   = lane >> 2;              // async staging: row_local 0..15
    const int cpos = lane & 3;               // LDS chunk position
    const int kcl  = cpos ^ ((rl >> 1) & 3); // global chunk to fetch

    f32x4 acc[4][4];
    for (int i = 0; i < 4; ++i)
        for (int j = 0; j < 4; ++j) { f32x4 z = {0.f, 0.f, 0.f, 0.f}; acc[i][j] = z; }

    const int nkb = K >> 5;
    for (int kb = 0; kb < nkb; ++kb) {
        __syncthreads();
        if constexpr (sizeof(AT) == 4) {
            for (int i = 0; i < 4; ++i) {    // fp32 A: manual convert-staging
                int id  = tid + i * 256;
                int row = id >> 3, q = id & 7;
                int kc = q >> 1, half = q & 1;
                float4 v = *(const float4*)((const float*)A + (size_t)(m0 + row) * K + kb * 32 + q * 4);
                ushort4 p;
                p.x = (unsigned short)f2bf(v.x);
                p.y = (unsigned short)f2bf(v.y);
                p.z = (unsigned short)f2bf(v.z);
                p.w = (unsigned short)f2bf(v.w);
                int swz = kc ^ ((row >> 1) & 3);
                *(ushort4*)(As + row * 32 + swz * 8 + half * 4) = p;
            }
        } else {
            for (int i = 0; i < 2; ++i) {    // bf16 A: async, 16 rows per instr
                int row = w * 32 + i * 16 + rl;
                gld16(As + (w * 32 + i * 16) * 32,
                      (const short*)A + (size_t)(m0 + row) * K + kb * 32 + kcl * 8);
            }
        }
        for (int i = 0; i < 2; ++i) {        // B always bf16 async
            int row = w * 32 + i * 16 + rl;
            gld16(Bs + (w * 32 + i * 16) * 32,
                  BT + (size_t)(n0 + row) * K + kb * 32 + kcl * 8);
        }
        __syncthreads();
        short8 af[4], bf[4];
        for (int mf = 0; mf < 4; ++mf) {
            int row = wr * 64 + mf * 16 + l15;
            af[mf] = *(const short8*)(As + row * 32 + ((quad ^ ((row >> 1) & 3)) << 3));
        }
        for (int nf = 0; nf < 4; ++nf) {
            int row = wc * 64 + nf * 16 + l15;
            bf[nf] = *(const short8*)(Bs + row * 32 + ((quad ^ ((row >> 1) & 3)) << 3));
        }
        for (int mf = 0; mf < 4; ++mf)
            for (int nf = 0; nf < 4; ++nf)
                acc[mf][nf] = __builtin_amdgcn_mfma_f32_16x16x32_bf16(af[mf], bf[nf], acc[mf][nf], 0, 0, 0);
    }

    // ---- epilogue A: transposed fts store
    for (int nf = 0; nf < 4; ++nf) {
        int col = n0 + wc * 64 + nf * 16 + l15;
        int h = col >> 6, dd = col & 63;
        for (int mf = 0; mf < 4; ++mf) {
            int m = m0 + wr * 64 + mf * 16 + quad * 4;
            int b = m >> 9, n = m & 511;
            ushort4 pk;
            pk.x = (unsigned short)f2bf(acc[mf][nf][0]);
            pk.y = (unsigned short)f2bf(acc[mf][nf][1]);
            pk.z = (unsigned short)f2bf(acc[mf][nf][2]);
            pk.w = (unsigned short)f2bf(acc[mf][nf][3]);
            *(ushort4*)(fts + (size_t)((h * 32 + b) * 64 + dd) * 512 + n) = pk;
        }
    }

    // ---- epilogue B: P/Q exp factors from fp32 acc. head = n0/64 + wc.
    {
        const int head = (n0 >> 6) + wc;
        float w1[4], w2[4];
        for (int nf = 0; nf < 4; ++nf) {
            w1[nf] = a1w[head * 64 + nf * 16 + l15];
            w2[nf] = a2w[head * 64 + nf * 16 + l15];
        }
        const float b1 = a1b[head], b2 = a2b[head];
        const int rsel = l15 & 3;
        for (int mf = 0; mf < 4; ++mf) {
            float g1[4], g2[4];
            for (int r = 0; r < 4; ++r) {
                float s1 = 0.f, s2 = 0.f;
                for (int nf = 0; nf < 4; ++nf) {
                    s1 += acc[mf][nf][r] * w1[nf];
                    s2 += acc[mf][nf][r] * w2[nf];
                }
                for (int m = 1; m < 16; m <<= 1) {
                    s1 += __shfl_xor(s1, m, 64);
                    s2 += __shfl_xor(s2, m, 64);
                }
                g1[r] = s1; g2[r] = s2;
            }
            float v1 = rsel == 0 ? g1[0] : rsel == 1 ? g1[1] : rsel == 2 ? g1[2] : g1[3];
            float v2 = rsel == 0 ? g2[0] : rsel == 1 ? g2[1] : rsel == 2 ? g2[2] : g2[3];
            if (l15 < 4) {
                int m = m0 + wr * 64 + mf * 16 + quad * 4 + rsel;
                int b = m >> 9, i = m & 511;
                int fi = (head * 32 + b) * 512 + i;
                float f1 = v1 + b1, f2 = v2 + b2;
                fbuf[0 * FN + fi] = __builtin_amdgcn_exp2f(f1 * L2E);
                fbuf[1 * FN + fi] = __builtin_amdgcn_exp2f(f1 * (0.01f * L2E));
                fbuf[2 * FN + fi] = __builtin_amdgcn_exp2f(f2 * L2E);
                fbuf[3 * FN + fi] = __builtin_amdgcn_exp2f(f2 * (0.01f * L2E));
            }
        }
    }
}

// ---------------------------------------------------------------------------
// Kernel 3: fused GAT attention. One block = (h, b, 128-row quarter).
//   e(i,j) = exp(leaky_relu(f1+f2)) = max(P1_i*P2_j, Q1_i*Q2_j)   (max trick)
//   O[i,:] = sum_j e * fts[j,:];  L[i] = sum_j e  (ones-column MFMA);
//   out = elu(O/L + fts[i,:])
// ---------------------------------------------------------------------------
template <typename OutT>
__global__ __launch_bounds__(256, 4)
void attn_kernel(const short* __restrict__ fts, const float* __restrict__ fbuf,
                 OutT* __restrict__ out) {
    __shared__ __align__(16) short fts_s[64 * 256];  // 32KB, swizzled
    __shared__ __align__(16) float p2_s[256];
    __shared__ __align__(16) float q2_s[256];

    const int tid  = threadIdx.x;
    const int lane = tid & 63, w = tid >> 6;
    const int quad = lane >> 4, l15 = lane & 15;
    const int bx   = blockIdx.x;
    const int h    = bx >> 7;
    const int b    = (bx >> 2) & 31;
    const int quarter = bx & 3;
    const int r0   = quarter * 128;
    const size_t fbase = (size_t)((h * 32 + b) * 64) * 512;
    const int fidx = (h * 32 + b) * 512;

    f32x4 acc[2][4], accL[2];
    for (int i = 0; i < 2; ++i) {
        f32x4 z = {0.f, 0.f, 0.f, 0.f};
        accL[i] = z;
        for (int j = 0; j < 4; ++j) acc[i][j] = z;
    }
    short8 onesv;
    for (int t = 0; t < 8; ++t) onesv[t] = (short)0x3F80;   // bf16 1.0

    float P1r[2], Q1r[2];
    for (int rt = 0; rt < 2; ++rt) {
        int i = fidx + r0 + w * 32 + rt * 16 + l15;
        P1r[rt] = fbuf[i];
        Q1r[rt] = fbuf[1 * FN + i];
    }

    for (int c = 0; c < 2; ++c) {
        __syncthreads();
        for (int i = 0; i < 8; ++i) {        // stage fts chunk (async, src-swizzled)
            int id = tid + i * 256;
            int dd = id >> 5, nc = id & 31;
            gld16(fts_s + (i * 256 + w * 64) * 8,
                  fts + fbase + dd * 512 + c * 256 + ((nc ^ (dd & 7)) << 3));
        }
        {
            int j = fidx + c * 256 + tid;
            p2_s[tid] = fbuf[2 * FN + j];
            q2_s[tid] = fbuf[3 * FN + j];
        }
        __syncthreads();

        for (int jb = 0; jb < 8; ++jb) {     // 32 j per step
            short8 bfr[4];
            for (int nf = 0; nf < 4; ++nf) {
                int col = nf * 16 + l15;
                bfr[nf] = *(const short8*)(fts_s + col * 256 + (((jb * 4 + quad) ^ (col & 7)) << 3));
            }
            int o = jb * 32 + quad * 8;
            f32x4 pa = *(const f32x4*)(p2_s + o), pb = *(const f32x4*)(p2_s + o + 4);
            f32x4 qa = *(const f32x4*)(q2_s + o), qb = *(const f32x4*)(q2_s + o + 4);
            float p2v[8] = {pa[0], pa[1], pa[2], pa[3], pb[0], pb[1], pb[2], pb[3]};
            float q2v[8] = {qa[0], qa[1], qa[2], qa[3], qb[0], qb[1], qb[2], qb[3]};

            for (int rt = 0; rt < 2; ++rt) { // E-frag in A-layout: m=l15, k=quad*8+t
                short8 ef;
                for (int t = 0; t < 8; ++t)
                    ef[t] = f2bf(fmaxf(P1r[rt] * p2v[t], Q1r[rt] * q2v[t]));
                for (int nf = 0; nf < 4; ++nf)
                    acc[rt][nf] = __builtin_amdgcn_mfma_f32_16x16x32_bf16(ef, bfr[nf], acc[rt][nf], 0, 0, 0);
                accL[rt] = __builtin_amdgcn_mfma_f32_16x16x32_bf16(ef, onesv, accL[rt], 0, 0, 0);
            }
        }
    }

    // ---- epilogue: normalize (L already per-row in C-layout), residual, ELU, store
    for (int rt = 0; rt < 2; ++rt) {
        float rinv[4];
        for (int r = 0; r < 4; ++r) rinv[r] = __builtin_amdgcn_rcpf(accL[rt][r]);
        int i0 = r0 + w * 32 + rt * 16 + quad * 4;
        for (int nf = 0; nf < 4; ++nf) {
            int col = nf * 16 + l15;
            ushort4 res = *(const ushort4*)(fts + fbase + col * 512 + i0);
            unsigned short rr[4] = {res.x, res.y, res.z, res.w};
            for (int r = 0; r < 4; ++r) {
                float val = acc[rt][nf][r] * rinv[r] + bf2f((short)rr[r]);
                if (val < 0.f) val = __builtin_amdgcn_exp2f(val * L2E) - 1.f;  // elu
                size_t oidx = (size_t)(b * 512 + i0 + r) * 512 + h * 64 + col;
                if constexpr (sizeof(OutT) == 4) out[oidx] = val;
                else                             out[oidx] = f2bf(val);
            }
        }
    }
}

// ---------------------------------------------------------------------------
extern "C" void kernel_launch(void* const* d_in, const int* in_sizes, int n_in,
                              void* d_out, int out_size, void* d_ws, size_t ws_size,
                              hipStream_t stream) {
    const float* x   = (const float*)d_in[0];   // (32,512,128) f32
    const float* W0  = (const float*)d_in[1];   // (8,128,64)
    const float* W1  = (const float*)d_in[2];   // (8,512,64)
    const float* a1w = (const float*)d_in[3];   // (2,8,64)
    const float* a1b = (const float*)d_in[4];   // (2,8)
    const float* a2w = (const float*)d_in[5];   // (2,8,64)
    const float* a2b = (const float*)d_in[6];   // (2,8)
    float* out = (float*)d_out;                 // (32,512,512) f32

    char* ws = (char*)d_ws;
    short* BT0  = (short*)(ws);                 // 512x128 bf16   (131072 B)
    short* BT1  = (short*)(ws + 131072);        // 512x512 bf16   (524288 B)
    float* fbuf = (float*)(ws + 655360);        // 4 x 131072 f32 (2097152 B)
    short* fts  = (short*)(ws + 2752512);       // (8,32,64,512) bf16 (16.78 MB)
    short* hbuf = (short*)d_out;                // bf16 hidden in d_out (overwritten later)

    wtrans_kernel<<<1280, 256, 0, stream>>>(W0, W1, BT0, BT1);

    // stack 0
    gemm_kernel<float><<<dim3(4, 128), 256, 0, stream>>>(x, BT0, fts, 128,
                                                         a1w, a1b, a2w, a2b, fbuf);
    attn_kernel<short><<<1024, 256, 0, stream>>>(fts, fbuf, hbuf);

    // stack 1
    gemm_kernel<short><<<dim3(4, 128), 256, 0, stream>>>(hbuf, BT1, fts, 512,
                                                         a1w + 512, a1b + 8, a2w + 512, a2b + 8, fbuf);
    attn_kernel<float><<<1024, 256, 0, stream>>>(fts, fbuf, out);
}

// Round 6
// 161.025 us; speedup vs baseline: 1.1203x; 1.0070x over previous
//
#include <hip/hip_runtime.h>
#include <hip/hip_bf16.h>
#include <stdint.h>

typedef __attribute__((ext_vector_type(8))) short short8;
typedef __attribute__((ext_vector_type(4))) float f32x4;

#define L2E 1.44269504f
#define FN  131072              // elements per f-array: H*B*N = 8*32*512

__device__ __forceinline__ short f2bf(float f) {
    unsigned u = __builtin_bit_cast(unsigned, f);
    return (short)((u + 0x8000u) >> 16);   // round-half-up to bf16
}
__device__ __forceinline__ float bf2f(short s) {
    unsigned u = ((unsigned)(unsigned short)s) << 16;
    return __builtin_bit_cast(float, u);
}

// async global->LDS, 16B per lane; LDS dest = wave-uniform base + lane*16
__device__ __forceinline__ void gld16(void* l, const void* g) {
    __builtin_amdgcn_global_load_lds(
        (const __attribute__((address_space(1))) unsigned*)g,
        (__attribute__((address_space(3))) unsigned*)l, 16, 0, 0);
}

// ---------------------------------------------------------------------------
// Kernel 1: transpose + fp32->bf16 convert W -> BT.
// ---------------------------------------------------------------------------
__global__ void wtrans_kernel(const float* __restrict__ W0, const float* __restrict__ W1,
                              short* __restrict__ BT0, short* __restrict__ BT1) {
    int idx = blockIdx.x * 256 + threadIdx.x;
    if (idx < 8 * 128 * 64) {
        int h = idx >> 13;
        int k = (idx >> 6) & 127;
        int dd = idx & 63;
        BT0[(h * 64 + dd) * 128 + k] = f2bf(W0[idx]);
    } else {
        int j = idx - 8 * 128 * 64;
        int h = j >> 15;
        int k = (j >> 6) & 511;
        int dd = j & 63;
        BT1[(h * 64 + dd) * 512 + k] = f2bf(W1[j]);
    }
}

// ---------------------------------------------------------------------------
// Kernel 2: GEMM  C(16384 x 512) = A(16384 x K) @ BT(512 x K)^T, bf16 MFMA.
// BK=64 (2 MFMA k-steps per stage) -> half the barrier drains of BK=32.
// fts written transposed per head: fts[(h*32+b)*64+dd][n] bf16.
// Epilogue computes f1/f2 = fts @ a-vec (+bias) from fp32 acc and stores
// P1=e^f1, Q1=e^{.01 f1}, P2=e^f2, Q2=e^{.01 f2}  (fbuf[0..3], idx (h*32+b)*512+i).
// LDS: unpadded 64-short rows, chunk swizzle g ^ (row&7) -> <=2-way banks.
// ---------------------------------------------------------------------------
template <typename AT>
__global__ __launch_bounds__(256, 2)
void gemm_kernel(const AT* __restrict__ A, const short* __restrict__ BT,
                 short* __restrict__ fts, int K,
                 const float* __restrict__ a1w, const float* __restrict__ a1b,
                 const float* __restrict__ a2w, const float* __restrict__ a2b,
                 float* __restrict__ fbuf) {
    __shared__ __align__(16) short As[128 * 64];   // 16 KB
    __shared__ __align__(16) short Bs[128 * 64];   // 16 KB

    const int tid  = threadIdx.x;
    const int lane = tid & 63;
    const int w    = tid >> 6;
    const int wr   = w >> 1, wc = w & 1;
    const int quad = lane >> 4, l15 = lane & 15;
    const int m0   = blockIdx.y * 128;
    const int n0   = blockIdx.x * 128;

    // async-staging lane map: 8 rows x 8 chunks per instr
    const int rl   = lane >> 3;        // row_local 0..7
    const int cpos = lane & 7;         // physical LDS chunk
    const int kcl  = cpos ^ rl;        // global chunk to fetch ((row&7)==rl)

    f32x4 acc[4][4];
    for (int i = 0; i < 4; ++i)
        for (int j = 0; j < 4; ++j) { f32x4 z = {0.f, 0.f, 0.f, 0.f}; acc[i][j] = z; }

    const int nkb = K >> 6;
    for (int kb = 0; kb < nkb; ++kb) {
        __syncthreads();
        if constexpr (sizeof(AT) == 4) {
            for (int i = 0; i < 8; ++i) {      // fp32 A: manual convert-staging
                int id  = tid + i * 256;
                int row = id >> 4, q = id & 15;    // q: 4-float subchunk
                int c = q >> 1, half = q & 1;
                float4 v = *(const float4*)((const float*)A + (size_t)(m0 + row) * K + kb * 64 + q * 4);
                ushort4 p;
                p.x = (unsigned short)f2bf(v.x);
                p.y = (unsigned short)f2bf(v.y);
                p.z = (unsigned short)f2bf(v.z);
                p.w = (unsigned short)f2bf(v.w);
                int swz = c ^ (row & 7);
                *(ushort4*)(As + row * 64 + swz * 8 + half * 4) = p;
            }
        } else {
            for (int i = 0; i < 4; ++i) {      // bf16 A: async, 8 rows per instr
                int rowb = w * 32 + i * 8;
                gld16(As + rowb * 64,
                      (const short*)A + (size_t)(m0 + rowb + rl) * K + kb * 64 + kcl * 8);
            }
        }
        for (int i = 0; i < 4; ++i) {          // B always bf16 async
            int rowb = w * 32 + i * 8;
            gld16(Bs + rowb * 64,
                  BT + (size_t)(n0 + rowb + rl) * K + kb * 64 + kcl * 8);
        }
        __syncthreads();
        short8 af[2][4], bf[2][4];
        for (int ks = 0; ks < 2; ++ks) {
            for (int mf = 0; mf < 4; ++mf) {
                int row = wr * 64 + mf * 16 + l15;
                af[ks][mf] = *(const short8*)(As + row * 64 + (((ks * 4 + quad) ^ (row & 7)) << 3));
            }
            for (int nf = 0; nf < 4; ++nf) {
                int row = wc * 64 + nf * 16 + l15;
                bf[ks][nf] = *(const short8*)(Bs + row * 64 + (((ks * 4 + quad) ^ (row & 7)) << 3));
            }
        }
        for (int ks = 0; ks < 2; ++ks)         // k-ascending: same acc order as BK=32
            for (int mf = 0; mf < 4; ++mf)
                for (int nf = 0; nf < 4; ++nf)
                    acc[mf][nf] = __builtin_amdgcn_mfma_f32_16x16x32_bf16(af[ks][mf], bf[ks][nf], acc[mf][nf], 0, 0, 0);
    }

    // ---- epilogue A: transposed fts store
    for (int nf = 0; nf < 4; ++nf) {
        int col = n0 + wc * 64 + nf * 16 + l15;
        int h = col >> 6, dd = col & 63;
        for (int mf = 0; mf < 4; ++mf) {
            int m = m0 + wr * 64 + mf * 16 + quad * 4;
            int b = m >> 9, n = m & 511;
            ushort4 pk;
            pk.x = (unsigned short)f2bf(acc[mf][nf][0]);
            pk.y = (unsigned short)f2bf(acc[mf][nf][1]);
            pk.z = (unsigned short)f2bf(acc[mf][nf][2]);
            pk.w = (unsigned short)f2bf(acc[mf][nf][3]);
            *(ushort4*)(fts + (size_t)((h * 32 + b) * 64 + dd) * 512 + n) = pk;
        }
    }

    // ---- epilogue B: P/Q exp factors from fp32 acc. head = n0/64 + wc.
    {
        const int head = (n0 >> 6) + wc;
        float w1[4], w2[4];
        for (int nf = 0; nf < 4; ++nf) {
            w1[nf] = a1w[head * 64 + nf * 16 + l15];
            w2[nf] = a2w[head * 64 + nf * 16 + l15];
        }
        const float b1 = a1b[head], b2 = a2b[head];
        const int rsel = l15 & 3;
        for (int mf = 0; mf < 4; ++mf) {
            float g1[4], g2[4];
            for (int r = 0; r < 4; ++r) {
                float s1 = 0.f, s2 = 0.f;
                for (int nf = 0; nf < 4; ++nf) {
                    s1 += acc[mf][nf][r] * w1[nf];
                    s2 += acc[mf][nf][r] * w2[nf];
                }
                for (int m = 1; m < 16; m <<= 1) {
                    s1 += __shfl_xor(s1, m, 64);
                    s2 += __shfl_xor(s2, m, 64);
                }
                g1[r] = s1; g2[r] = s2;
            }
            float v1 = rsel == 0 ? g1[0] : rsel == 1 ? g1[1] : rsel == 2 ? g1[2] : g1[3];
            float v2 = rsel == 0 ? g2[0] : rsel == 1 ? g2[1] : rsel == 2 ? g2[2] : g2[3];
            if (l15 < 4) {
                int m = m0 + wr * 64 + mf * 16 + quad * 4 + rsel;
                int b = m >> 9, i = m & 511;
                int fi = (head * 32 + b) * 512 + i;
                float f1 = v1 + b1, f2 = v2 + b2;
                fbuf[0 * FN + fi] = __builtin_amdgcn_exp2f(f1 * L2E);
                fbuf[1 * FN + fi] = __builtin_amdgcn_exp2f(f1 * (0.01f * L2E));
                fbuf[2 * FN + fi] = __builtin_amdgcn_exp2f(f2 * L2E);
                fbuf[3 * FN + fi] = __builtin_amdgcn_exp2f(f2 * (0.01f * L2E));
            }
        }
    }
}

// ---------------------------------------------------------------------------
// Kernel 3: fused GAT attention. One block = (h, b, 128-row quarter).
//   e(i,j) = exp(leaky_relu(f1+f2)) = max(P1_i*P2_j, Q1_i*Q2_j)   (max trick)
//   O[i,:] = sum_j e * fts[j,:];  L[i] = sum_j e  (ones-column MFMA);
//   out = elu(O/L + fts[i,:])
// ---------------------------------------------------------------------------
template <typename OutT>
__global__ __launch_bounds__(256, 4)
void attn_kernel(const short* __restrict__ fts, const float* __restrict__ fbuf,
                 OutT* __restrict__ out) {
    __shared__ __align__(16) short fts_s[64 * 256];  // 32KB, swizzled
    __shared__ __align__(16) float p2_s[256];
    __shared__ __align__(16) float q2_s[256];

    const int tid  = threadIdx.x;
    const int lane = tid & 63, w = tid >> 6;
    const int quad = lane >> 4, l15 = lane & 15;
    const int bx   = blockIdx.x;
    const int h    = bx >> 7;
    const int b    = (bx >> 2) & 31;
    const int quarter = bx & 3;
    const int r0   = quarter * 128;
    const size_t fbase = (size_t)((h * 32 + b) * 64) * 512;
    const int fidx = (h * 32 + b) * 512;

    f32x4 acc[2][4], accL[2];
    for (int i = 0; i < 2; ++i) {
        f32x4 z = {0.f, 0.f, 0.f, 0.f};
        accL[i] = z;
        for (int j = 0; j < 4; ++j) acc[i][j] = z;
    }
    short8 onesv;
    for (int t = 0; t < 8; ++t) onesv[t] = (short)0x3F80;   // bf16 1.0

    float P1r[2], Q1r[2];
    for (int rt = 0; rt < 2; ++rt) {
        int i = fidx + r0 + w * 32 + rt * 16 + l15;
        P1r[rt] = fbuf[i];
        Q1r[rt] = fbuf[1 * FN + i];
    }

    for (int c = 0; c < 2; ++c) {
        __syncthreads();
        for (int i = 0; i < 8; ++i) {        // stage fts chunk (async, src-swizzled)
            int id = tid + i * 256;
            int dd = id >> 5, nc = id & 31;
            gld16(fts_s + (i * 256 + w * 64) * 8,
                  fts + fbase + dd * 512 + c * 256 + ((nc ^ (dd & 7)) << 3));
        }
        {
            int j = fidx + c * 256 + tid;
            p2_s[tid] = fbuf[2 * FN + j];
            q2_s[tid] = fbuf[3 * FN + j];
        }
        __syncthreads();

        for (int jb = 0; jb < 8; ++jb) {     // 32 j per step
            short8 bfr[4];
            for (int nf = 0; nf < 4; ++nf) {
                int col = nf * 16 + l15;
                bfr[nf] = *(const short8*)(fts_s + col * 256 + (((jb * 4 + quad) ^ (col & 7)) << 3));
            }
            int o = jb * 32 + quad * 8;
            f32x4 pa = *(const f32x4*)(p2_s + o), pb = *(const f32x4*)(p2_s + o + 4);
            f32x4 qa = *(const f32x4*)(q2_s + o), qb = *(const f32x4*)(q2_s + o + 4);
            float p2v[8] = {pa[0], pa[1], pa[2], pa[3], pb[0], pb[1], pb[2], pb[3]};
            float q2v[8] = {qa[0], qa[1], qa[2], qa[3], qb[0], qb[1], qb[2], qb[3]};

            for (int rt = 0; rt < 2; ++rt) { // E-frag in A-layout: m=l15, k=quad*8+t
                short8 ef;
                for (int t = 0; t < 8; ++t)
                    ef[t] = f2bf(fmaxf(P1r[rt] * p2v[t], Q1r[rt] * q2v[t]));
                for (int nf = 0; nf < 4; ++nf)
                    acc[rt][nf] = __builtin_amdgcn_mfma_f32_16x16x32_bf16(ef, bfr[nf], acc[rt][nf], 0, 0, 0);
                accL[rt] = __builtin_amdgcn_mfma_f32_16x16x32_bf16(ef, onesv, accL[rt], 0, 0, 0);
            }
        }
    }

    // ---- epilogue: normalize (L already per-row in C-layout), residual, ELU, store
    for (int rt = 0; rt < 2; ++rt) {
        float rinv[4];
        for (int r = 0; r < 4; ++r) rinv[r] = __builtin_amdgcn_rcpf(accL[rt][r]);
        int i0 = r0 + w * 32 + rt * 16 + quad * 4;
        for (int nf = 0; nf < 4; ++nf) {
            int col = nf * 16 + l15;
            ushort4 res = *(const ushort4*)(fts + fbase + col * 512 + i0);
            unsigned short rr[4] = {res.x, res.y, res.z, res.w};
            for (int r = 0; r < 4; ++r) {
                float val = acc[rt][nf][r] * rinv[r] + bf2f((short)rr[r]);
                if (val < 0.f) val = __builtin_amdgcn_exp2f(val * L2E) - 1.f;  // elu
                size_t oidx = (size_t)(b * 512 + i0 + r) * 512 + h * 64 + col;
                if constexpr (sizeof(OutT) == 4) out[oidx] = val;
                else                             out[oidx] = f2bf(val);
            }
        }
    }
}

// ---------------------------------------------------------------------------
extern "C" void kernel_launch(void* const* d_in, const int* in_sizes, int n_in,
                              void* d_out, int out_size, void* d_ws, size_t ws_size,
                              hipStream_t stream) {
    const float* x   = (const float*)d_in[0];   // (32,512,128) f32
    const float* W0  = (const float*)d_in[1];   // (8,128,64)
    const float* W1  = (const float*)d_in[2];   // (8,512,64)
    const float* a1w = (const float*)d_in[3];   // (2,8,64)
    const float* a1b = (const float*)d_in[4];   // (2,8)
    const float* a2w = (const float*)d_in[5];   // (2,8,64)
    const float* a2b = (const float*)d_in[6];   // (2,8)
    float* out = (float*)d_out;                 // (32,512,512) f32

    char* ws = (char*)d_ws;
    short* BT0  = (short*)(ws);                 // 512x128 bf16   (131072 B)
    short* BT1  = (short*)(ws + 131072);        // 512x512 bf16   (524288 B)
    float* fbuf = (float*)(ws + 655360);        // 4 x 131072 f32 (2097152 B)
    short* fts  = (short*)(ws + 2752512);       // (8,32,64,512) bf16 (16.78 MB)
    short* hbuf = (short*)d_out;                // bf16 hidden in d_out (overwritten later)

    wtrans_kernel<<<1280, 256, 0, stream>>>(W0, W1, BT0, BT1);

    // stack 0
    gemm_kernel<float><<<dim3(4, 128), 256, 0, stream>>>(x, BT0, fts, 128,
                                                         a1w, a1b, a2w, a2b, fbuf);
    attn_kernel<short><<<1024, 256, 0, stream>>>(fts, fbuf, hbuf);

    // stack 1
    gemm_kernel<short><<<dim3(4, 128), 256, 0, stream>>>(hbuf, BT1, fts, 512,
                                                         a1w + 512, a1b + 8, a2w + 512, a2b + 8, fbuf);
    attn_kernel<float><<<1024, 256, 0, stream>>>(fts, fbuf, out);
}